// Round 5
// baseline (386.026 us; speedup 1.0000x reference)
//
#include <hip/hip_runtime.h>
#include <hip/hip_bf16.h>

typedef unsigned short u16;
typedef unsigned int u32;
typedef __attribute__((ext_vector_type(8))) short short8;
typedef __attribute__((ext_vector_type(4))) float f32x4;
typedef __attribute__((ext_vector_type(16))) float f32x16;
typedef __attribute__((ext_vector_type(4))) u32 u32x4;

// ---- helpers ----------------------------------------------------------

__device__ __forceinline__ u16 f2b(float f) {
  unsigned u = __float_as_uint(f);
  u = (u + 0x7FFFu + ((u >> 16) & 1u)) >> 16;  // RNE
  return (u16)u;
}

__device__ __forceinline__ u32 pkbf(float lo, float hi) {
  __hip_bfloat162 b = __float22bfloat162_rn(make_float2(lo, hi));  // v_cvt_pk_bf16_f32
  u32 r;
  __builtin_memcpy(&r, &b, 4);
  return r;
}

__device__ __forceinline__ void gload16(const void* g, void* l) {
  __builtin_amdgcn_global_load_lds(
      (const __attribute__((address_space(1))) void*)g,
      (__attribute__((address_space(3))) void*)l, 16, 0, 0);
}

// ---- fp32 -> bf16 bulk convert (optional scale fold) -------------------

__global__ __launch_bounds__(256) void f2bf_kernel(const float* __restrict__ in,
                                                   u16* __restrict__ out, int n,
                                                   float scale) {
  int i = (blockIdx.x * 256 + threadIdx.x) * 4;
  if (i >= n) return;
  float4 v = *(const float4*)(in + i);
  unsigned p0 = (unsigned)f2b(v.x * scale) | ((unsigned)f2b(v.y * scale) << 16);
  unsigned p1 = (unsigned)f2b(v.z * scale) | ((unsigned)f2b(v.w * scale) << 16);
  *(uint2*)(out + i) = make_uint2(p0, p1);
}

// ---- bf16 transpose: V[4096][1024] -> Vt[1024][4096] -------------------

__global__ __launch_bounds__(256) void transpose_kernel(const u16* __restrict__ V,
                                                        u16* __restrict__ Vt) {
  __shared__ u16 t[32][33];
  int bx = blockIdx.x;
  int by = blockIdx.y;
  int c = threadIdx.x & 31, r4 = threadIdx.x >> 5;
#pragma unroll
  for (int i = 0; i < 4; ++i) {
    int row = r4 * 4 + i;
    t[row][c] = V[(size_t)(by * 32 + row) * 1024 + bx * 32 + c];
  }
  __syncthreads();
#pragma unroll
  for (int i = 0; i < 4; ++i) {
    int row = r4 * 4 + i;
    Vt[(size_t)(bx * 32 + row) * 4096 + by * 32 + c] = t[c][row];
  }
}

// ---- GEMM: C[4096][1024] = A[4096][1024] @ B[1024][1024]^T (bf16) ------

__device__ __forceinline__ void storeC(u16* C, size_t idx, float v) { C[idx] = f2b(v); }
__device__ __forceinline__ void storeC(float* C, size_t idx, float v) { C[idx] = v; }

template <typename OutT>
__device__ __forceinline__ void gemm_body(const u16* __restrict__ A,
                                          const u16* __restrict__ B,
                                          OutT* __restrict__ C) {
  __shared__ __align__(16) u16 lA[128 * 32];
  __shared__ __align__(16) u16 lB[128 * 32];
  const int tid = threadIdx.x;
  const int w = tid >> 6, lane = tid & 63, g = lane >> 4, lr = lane & 15;
  const int wr = w >> 1, wc = w & 1;
  const int m0 = blockIdx.y * 128, n0 = blockIdx.x * 128;

  f32x4 acc[4][4] = {};

  for (int k0 = 0; k0 < 1024; k0 += 32) {
#pragma unroll
    for (int j = 0; j < 2; ++j) {
      int c = tid + j * 256;
      gload16(A + (size_t)(m0 + (c >> 2)) * 1024 + k0 + (c & 3) * 8,
              &lA[(j * 256 + w * 64) * 8]);
      gload16(B + (size_t)(n0 + (c >> 2)) * 1024 + k0 + (c & 3) * 8,
              &lB[(j * 256 + w * 64) * 8]);
    }
    __syncthreads();

    short8 af[4], bf[4];
#pragma unroll
    for (int i = 0; i < 4; ++i) {
      af[i] = *(const short8*)&lA[(wr * 64 + i * 16 + lr) * 32 + g * 8];
      bf[i] = *(const short8*)&lB[(wc * 64 + i * 16 + lr) * 32 + g * 8];
    }
#pragma unroll
    for (int mi = 0; mi < 4; ++mi)
#pragma unroll
      for (int ni = 0; ni < 4; ++ni)
        acc[mi][ni] =
            __builtin_amdgcn_mfma_f32_16x16x32_bf16(af[mi], bf[ni], acc[mi][ni], 0, 0, 0);
    __syncthreads();
  }

#pragma unroll
  for (int mi = 0; mi < 4; ++mi)
#pragma unroll
    for (int ni = 0; ni < 4; ++ni)
#pragma unroll
      for (int r = 0; r < 4; ++r) {
        size_t row = (size_t)(m0 + wr * 64 + mi * 16 + g * 4 + r);
        size_t col = (size_t)(n0 + wc * 64 + ni * 16 + lr);
        storeC(C, row * 1024 + col, acc[mi][ni][r]);
      }
}

__global__ __launch_bounds__(256) void gemm_qkv_kernel(
    const u16* __restrict__ A, const u16* __restrict__ W0, const u16* __restrict__ W1,
    const u16* __restrict__ W2, u16* __restrict__ C0, u16* __restrict__ C1,
    u16* __restrict__ C2) {
  int z = blockIdx.z;
  const u16* B = (z == 0) ? W0 : (z == 1) ? W1 : W2;
  u16* C = (z == 0) ? C0 : (z == 1) ? C1 : C2;
  gemm_body<u16>(A, B, C);
}

__global__ __launch_bounds__(256) void gemm_out_kernel(const u16* __restrict__ A,
                                                       const u16* __restrict__ B,
                                                       float* __restrict__ C) {
  gemm_body<float>(A, B, C);
}

// ---- flash attention, swapped-operand 32x32, KV-split x2 ---------------
// block = 128 thr = 2 waves sharing ONE 32-row q-subtile of one head.
// wave0: key-tiles [0, ntt/2), wave1: [ntt/2, ntt) incl. diagonal; flash
// combine via LDS. 2048 blocks -> 4096 waves (16/CU). Heavy subtiles first.
// S^T = mfma(K, Q): col=query=lane&31, row=key=crow(r,hi)=(r&3)+8*(r>>2)+4*hi.
// O^T = mfma(V^T, P^T): col=query (lane-local), row=d.
// Q pre-scaled by 0.125*log2e -> softmax in exp2 domain. Mask = -30000.

#define NEGINF (-30000.0f)

__global__ __launch_bounds__(128, 4) void attn_kernel(const u16* __restrict__ Qg,
                                                      const u16* __restrict__ Kg,
                                                      const u16* __restrict__ Vtg,
                                                      u16* __restrict__ Og) {
  __shared__ __align__(16) float lOf[64 * 32];  // 8KB: wave0's O^T (f32)
  __shared__ float lm[32], ll[32];
  __shared__ __align__(16) u16 lOut[32 * 64];   // 4KB: bf16 out transpose
  const int tid = threadIdx.x, w = tid >> 6, lane = tid & 63;
  const int l31 = lane & 31, hi = lane >> 5;
  const int bid = blockIdx.x;
  const int h = bid & 15;                 // head (fixed XCD: bid%8 = h%8)
  const int ss = 127 - (bid >> 4);        // q-subtile, heavy first
  const int qs = ss * 32;                 // first q row
  const int ntt = (ss + 2) >> 1;          // causal 64-key tiles
  const int ks0 = w ? (ntt >> 1) : 0;     // this wave's tile range
  const int ks1 = w ? ntt : (ntt >> 1);

  const u16* Qp = Qg + (size_t)(qs + l31) * 1024 + h * 64 + hi * 8;
  const u16* Kp = Kg + (size_t)l31 * 1024 + h * 64 + hi * 8;
  const u16* Vp = Vtg + (size_t)(h * 64 + l31) * 4096 + hi * 8;

  short8 qf[4];
#pragma unroll
  for (int kc = 0; kc < 4; ++kc) qf[kc] = *(const short8*)(Qp + kc * 16);

  short8 kf[2][4], vf[2][4];
  {
    const u16* K0 = Kp + (size_t)ks0 * 64 * 1024;
    const u16* V0 = Vp + ks0 * 64;
#pragma unroll
    for (int kt2 = 0; kt2 < 2; ++kt2)
#pragma unroll
      for (int kc = 0; kc < 4; ++kc)
        kf[kt2][kc] = *(const short8*)(K0 + (size_t)kt2 * 32768 + kc * 16);
#pragma unroll
    for (int dt = 0; dt < 2; ++dt)
#pragma unroll
      for (int ks = 0; ks < 4; ++ks)
        vf[dt][ks] = *(const short8*)(V0 + (size_t)dt * 131072 + ks * 16);
  }

  f32x16 ot[2] = {};
  float m = NEGINF, lsum = 0.f;

  for (int kt = ks0; kt < ks1; ++kt) {
    const int kbase = kt * 64;

    // S^T = K · Q^T  (8 mfma)
    f32x16 st[2] = {};
#pragma unroll
    for (int kt2 = 0; kt2 < 2; ++kt2)
#pragma unroll
      for (int kc = 0; kc < 4; ++kc)
        st[kt2] = __builtin_amdgcn_mfma_f32_32x32x16_bf16(kf[kt2][kc], qf[kc],
                                                          st[kt2], 0, 0, 0);

    if (kt + 1 < ks1) {  // prefetch next K tile; overlaps softmax+PV
      const u16* Kn = Kp + (size_t)(kbase + 64) * 1024;
#pragma unroll
      for (int kt2 = 0; kt2 < 2; ++kt2)
#pragma unroll
        for (int kc = 0; kc < 4; ++kc)
          kf[kt2][kc] = *(const short8*)(Kn + (size_t)kt2 * 32768 + kc * 16);
    }

    if (kt == ntt - 1) {  // causal mask, diagonal tile only (wave1)
      const int q = qs + l31;
#pragma unroll
      for (int kt2 = 0; kt2 < 2; ++kt2)
#pragma unroll
        for (int r = 0; r < 16; ++r) {
          int key = kbase + kt2 * 32 + (r & 3) + 8 * (r >> 2) + 4 * hi;
          if (key > q) st[kt2][r] = NEGINF;
        }
    }

    // row max: in-lane tree + one cross-half exchange
    float pm;
    {
      float a0 = NEGINF, a1 = NEGINF, a2 = NEGINF, a3 = NEGINF;
#pragma unroll
      for (int kt2 = 0; kt2 < 2; ++kt2)
#pragma unroll
        for (int r = 0; r < 4; ++r) {
          a0 = fmaxf(a0, st[kt2][r]);
          a1 = fmaxf(a1, st[kt2][r + 4]);
          a2 = fmaxf(a2, st[kt2][r + 8]);
          a3 = fmaxf(a3, st[kt2][r + 12]);
        }
      pm = fmaxf(fmaxf(a0, a1), fmaxf(a2, a3));
      pm = fmaxf(pm, __shfl_xor(pm, 32, 64));
    }

    // always-rescale online softmax (log2 domain)
    {
      float mn = fmaxf(m, pm);
      float al = exp2f(m - mn);
      lsum *= al;
#pragma unroll
      for (int dt = 0; dt < 2; ++dt)
#pragma unroll
        for (int r = 0; r < 16; ++r) ot[dt][r] *= al;
      m = mn;
    }

    float ps = 0.f;
#pragma unroll
    for (int kt2 = 0; kt2 < 2; ++kt2)
#pragma unroll
      for (int r = 0; r < 16; ++r) {
        float p = exp2f(st[kt2][r] - m);
        st[kt2][r] = p;
        ps += p;
      }
    ps += __shfl_xor(ps, 32, 64);
    lsum += ps;

    // P -> bf16 B-fragments (v_cvt_pk via __float22bfloat162_rn)
    // pa[ks] elem e holds P^T[key = 16ks + 8*hi + e][query l31]
    short8 pa[4];
#pragma unroll
    for (int ks = 0; ks < 4; ++ks) {
      const f32x16 P = st[ks >> 1];
      const int b = 8 * (ks & 1);
      u32 pk0 = pkbf(P[b + 0], P[b + 1]);  // keys 16ks+{0,1}+4hi
      u32 pk1 = pkbf(P[b + 2], P[b + 3]);  // keys 16ks+{2,3}+4hi
      u32 pk2 = pkbf(P[b + 4], P[b + 5]);  // keys 16ks+8+{0,1}+4hi
      u32 pk3 = pkbf(P[b + 6], P[b + 7]);  // keys 16ks+8+{2,3}+4hi
      u32 s0 = (u32)__shfl_xor((int)pk0, 32, 64);
      u32 s1 = (u32)__shfl_xor((int)pk1, 32, 64);
      u32 s2 = (u32)__shfl_xor((int)pk2, 32, 64);
      u32 s3 = (u32)__shfl_xor((int)pk3, 32, 64);
      u32x4 t;
      t.x = hi ? s2 : pk0;
      t.y = hi ? s3 : pk1;
      t.z = hi ? pk2 : s0;
      t.w = hi ? pk3 : s1;
      pa[ks] = __builtin_bit_cast(short8, t);
    }

    // O^T += V^T · P^T  (8 mfma)
#pragma unroll
    for (int dt = 0; dt < 2; ++dt)
#pragma unroll
      for (int ks = 0; ks < 4; ++ks)
        ot[dt] = __builtin_amdgcn_mfma_f32_32x32x16_bf16(vf[dt][ks], pa[ks],
                                                         ot[dt], 0, 0, 0);

    if (kt + 1 < ks1) {  // prefetch next V tile
      const u16* Vn = Vp + kbase + 64;
#pragma unroll
      for (int dt = 0; dt < 2; ++dt)
#pragma unroll
        for (int ks = 0; ks < 4; ++ks)
          vf[dt][ks] = *(const short8*)(Vn + (size_t)dt * 131072 + ks * 16);
    }
  }

  // ---- flash combine of the two KV-halves ------------------------------
  if (w == 0) {
#pragma unroll
    for (int dt = 0; dt < 2; ++dt)
#pragma unroll
      for (int r = 0; r < 16; ++r) {
        int d = dt * 32 + (r & 3) + 8 * (r >> 2) + 4 * hi;
        lOf[d * 32 + l31] = ot[dt][r];
      }
    if (hi == 0) { lm[l31] = m; ll[l31] = lsum; }
  }
  __syncthreads();
  if (w == 1) {
    float mA = lm[l31], lA = ll[l31];
    float mm = fmaxf(mA, m);
    float wA = exp2f(mA - mm), wB = exp2f(m - mm);
    float inv = 1.0f / (lA * wA + lsum * wB);
    char* pw = (char*)lOut;
#pragma unroll
    for (int dt = 0; dt < 2; ++dt)
#pragma unroll
      for (int r = 0; r < 16; ++r) {
        int d = dt * 32 + (r & 3) + 8 * (r >> 2) + 4 * hi;
        float val = (lOf[d * 32 + l31] * wA + ot[dt][r] * wB) * inv;
        *(u16*)(pw + l31 * 128 + ((d * 2) ^ ((l31 & 7) << 4))) = f2b(val);
      }
  }
  __syncthreads();
  if (w == 1) {
    const char* pw = (const char*)lOut;
    const int row = lane >> 1;
#pragma unroll
    for (int ii = 0; ii < 4; ++ii) {
      int c = (lane & 1) * 4 + ii;
      short8 v = *(const short8*)(pw + row * 128 + ((c * 16) ^ ((row & 7) << 4)));
      *(short8*)(Og + (size_t)(qs + row) * 1024 + h * 64 + c * 8) = v;
    }
  }
}

// ---- launcher ----------------------------------------------------------

extern "C" void kernel_launch(void* const* d_in, const int* in_sizes, int n_in,
                              void* d_out, int out_size, void* d_ws, size_t ws_size,
                              hipStream_t stream) {
  const float* x = (const float*)d_in[0];
  const float* Wq = (const float*)d_in[1];
  const float* Wk = (const float*)d_in[2];
  const float* Wv = (const float*)d_in[3];
  const float* Wo = (const float*)d_in[4];
  float* out = (float*)d_out;
  char* ws = (char*)d_ws;
  const size_t MB = 1024 * 1024;

  u16* xb  = (u16*)(ws);
  u16* wqb = (u16*)(ws + 8 * MB);
  u16* wkb = (u16*)(ws + 10 * MB);
  u16* wvb = (u16*)(ws + 12 * MB);
  u16* wob = (u16*)(ws + 14 * MB);
  u16* Qb  = (u16*)(ws + 16 * MB);
  u16* Kb  = (u16*)(ws + 24 * MB);
  u16* Vb  = (u16*)(ws + 32 * MB);
  u16* Vtb = (u16*)(ws + 40 * MB);
  u16* att = xb;

  // 0.125 = 1/sqrt(D); *log2(e) so softmax runs in exp2 domain
  const float qscale = 0.125f * 1.4426950408889634f;

  f2bf_kernel<<<4096, 256, 0, stream>>>(x, xb, 4096 * 1024, 1.f);
  f2bf_kernel<<<1024, 256, 0, stream>>>(Wq, wqb, 1024 * 1024, qscale);
  f2bf_kernel<<<1024, 256, 0, stream>>>(Wk, wkb, 1024 * 1024, 1.f);
  f2bf_kernel<<<1024, 256, 0, stream>>>(Wv, wvb, 1024 * 1024, 1.f);
  f2bf_kernel<<<1024, 256, 0, stream>>>(Wo, wob, 1024 * 1024, 1.f);

  gemm_qkv_kernel<<<dim3(8, 32, 3), 256, 0, stream>>>(xb, wqb, wkb, wvb, Qb, Kb, Vb);
  transpose_kernel<<<dim3(32, 128), 256, 0, stream>>>(Vb, Vtb);
  attn_kernel<<<2048, 128, 0, stream>>>(Qb, Kb, Vtb, att);
  gemm_out_kernel<<<dim3(8, 32), 256, 0, stream>>>(att, wob, out);
}

// Round 6
// 220.673 us; speedup vs baseline: 1.7493x; 1.7493x over previous
//
#include <hip/hip_runtime.h>
#include <hip/hip_bf16.h>

typedef unsigned short u16;
typedef unsigned int u32;
typedef __attribute__((ext_vector_type(8))) short short8;
typedef __attribute__((ext_vector_type(4))) float f32x4;
typedef __attribute__((ext_vector_type(16))) float f32x16;
typedef __attribute__((ext_vector_type(4))) u32 u32x4;

// ---- helpers ----------------------------------------------------------

__device__ __forceinline__ u16 f2b(float f) {
  unsigned u = __float_as_uint(f);
  u = (u + 0x7FFFu + ((u >> 16) & 1u)) >> 16;  // RNE
  return (u16)u;
}

__device__ __forceinline__ u32 pkbf(float lo, float hi) {
  __hip_bfloat162 b = __float22bfloat162_rn(make_float2(lo, hi));  // v_cvt_pk_bf16_f32
  u32 r;
  __builtin_memcpy(&r, &b, 4);
  return r;
}

__device__ __forceinline__ void gload16(const void* g, void* l) {
  __builtin_amdgcn_global_load_lds(
      (const __attribute__((address_space(1))) void*)g,
      (__attribute__((address_space(3))) void*)l, 16, 0, 0);
}

// ---- fp32 -> bf16 bulk convert (optional scale fold) -------------------

__global__ __launch_bounds__(256) void f2bf_kernel(const float* __restrict__ in,
                                                   u16* __restrict__ out, int n,
                                                   float scale) {
  int i = (blockIdx.x * 256 + threadIdx.x) * 4;
  if (i >= n) return;
  float4 v = *(const float4*)(in + i);
  unsigned p0 = (unsigned)f2b(v.x * scale) | ((unsigned)f2b(v.y * scale) << 16);
  unsigned p1 = (unsigned)f2b(v.z * scale) | ((unsigned)f2b(v.w * scale) << 16);
  *(uint2*)(out + i) = make_uint2(p0, p1);
}

// ---- bf16 transpose: V[4096][1024] -> Vt[1024][4096] -------------------

__global__ __launch_bounds__(256) void transpose_kernel(const u16* __restrict__ V,
                                                        u16* __restrict__ Vt) {
  __shared__ u16 t[32][33];
  int bx = blockIdx.x;
  int by = blockIdx.y;
  int c = threadIdx.x & 31, r4 = threadIdx.x >> 5;
#pragma unroll
  for (int i = 0; i < 4; ++i) {
    int row = r4 * 4 + i;
    t[row][c] = V[(size_t)(by * 32 + row) * 1024 + bx * 32 + c];
  }
  __syncthreads();
#pragma unroll
  for (int i = 0; i < 4; ++i) {
    int row = r4 * 4 + i;
    Vt[(size_t)(bx * 32 + row) * 4096 + by * 32 + c] = t[c][row];
  }
}

// ---- GEMM: C[4096][1024] = A[4096][1024] @ B[1024][1024]^T (bf16) ------

__device__ __forceinline__ void storeC(u16* C, size_t idx, float v) { C[idx] = f2b(v); }
__device__ __forceinline__ void storeC(float* C, size_t idx, float v) { C[idx] = v; }

template <typename OutT>
__device__ __forceinline__ void gemm_body(const u16* __restrict__ A,
                                          const u16* __restrict__ B,
                                          OutT* __restrict__ C) {
  __shared__ __align__(16) u16 lA[128 * 32];
  __shared__ __align__(16) u16 lB[128 * 32];
  const int tid = threadIdx.x;
  const int w = tid >> 6, lane = tid & 63, g = lane >> 4, lr = lane & 15;
  const int wr = w >> 1, wc = w & 1;
  const int m0 = blockIdx.y * 128, n0 = blockIdx.x * 128;

  f32x4 acc[4][4] = {};

  for (int k0 = 0; k0 < 1024; k0 += 32) {
#pragma unroll
    for (int j = 0; j < 2; ++j) {
      int c = tid + j * 256;
      gload16(A + (size_t)(m0 + (c >> 2)) * 1024 + k0 + (c & 3) * 8,
              &lA[(j * 256 + w * 64) * 8]);
      gload16(B + (size_t)(n0 + (c >> 2)) * 1024 + k0 + (c & 3) * 8,
              &lB[(j * 256 + w * 64) * 8]);
    }
    __syncthreads();

    short8 af[4], bf[4];
#pragma unroll
    for (int i = 0; i < 4; ++i) {
      af[i] = *(const short8*)&lA[(wr * 64 + i * 16 + lr) * 32 + g * 8];
      bf[i] = *(const short8*)&lB[(wc * 64 + i * 16 + lr) * 32 + g * 8];
    }
#pragma unroll
    for (int mi = 0; mi < 4; ++mi)
#pragma unroll
      for (int ni = 0; ni < 4; ++ni)
        acc[mi][ni] =
            __builtin_amdgcn_mfma_f32_16x16x32_bf16(af[mi], bf[ni], acc[mi][ni], 0, 0, 0);
    __syncthreads();
  }

#pragma unroll
  for (int mi = 0; mi < 4; ++mi)
#pragma unroll
    for (int ni = 0; ni < 4; ++ni)
#pragma unroll
      for (int r = 0; r < 4; ++r) {
        size_t row = (size_t)(m0 + wr * 64 + mi * 16 + g * 4 + r);
        size_t col = (size_t)(n0 + wc * 64 + ni * 16 + lr);
        storeC(C, row * 1024 + col, acc[mi][ni][r]);
      }
}

__global__ __launch_bounds__(256) void gemm_qkv_kernel(
    const u16* __restrict__ A, const u16* __restrict__ W0, const u16* __restrict__ W1,
    const u16* __restrict__ W2, u16* __restrict__ C0, u16* __restrict__ C1,
    u16* __restrict__ C2) {
  int z = blockIdx.z;
  const u16* B = (z == 0) ? W0 : (z == 1) ? W1 : W2;
  u16* C = (z == 0) ? C0 : (z == 1) ? C1 : C2;
  gemm_body<u16>(A, B, C);
}

__global__ __launch_bounds__(256) void gemm_out_kernel(const u16* __restrict__ A,
                                                       const u16* __restrict__ B,
                                                       float* __restrict__ C) {
  gemm_body<float>(A, B, C);
}

// ---- flash attention, swapped-operand 32x32, KV-split x2 ---------------
// block = 128 thr = 2 waves sharing ONE 32-row q-subtile of one head.
// 32-KEY tiles (register diet: kf/vf/st/pa halved vs 64-key -> ~130 VGPR,
// no spill under __launch_bounds__(128,3), 3 waves/SIMD).
// wave0: key-tiles [0, ntt/2), wave1: [ntt/2, ntt) incl. diagonal; flash
// combine via LDS. 2048 blocks. Heavy subtiles first.
// S^T = mfma(K, Q): col=query=lane&31, row=key=(r&3)+8*(r>>2)+4*hi.
// O^T = mfma(V^T, P^T): col=query (lane-local), row=d.
// Q pre-scaled by 0.125*log2e -> softmax in exp2 domain. Mask = -30000.

#define NEGINF (-30000.0f)

__global__ __launch_bounds__(128, 3) void attn_kernel(const u16* __restrict__ Qg,
                                                      const u16* __restrict__ Kg,
                                                      const u16* __restrict__ Vtg,
                                                      u16* __restrict__ Og) {
  __shared__ __align__(16) float lOf[64 * 32];  // 8KB: wave0's O^T (f32)
  __shared__ float lm[32], ll[32];
  __shared__ __align__(16) u16 lOut[32 * 64];   // 4KB: bf16 out transpose
  const int tid = threadIdx.x, w = tid >> 6, lane = tid & 63;
  const int l31 = lane & 31, hi = lane >> 5;
  const int bid = blockIdx.x;
  const int h = bid & 15;                 // head (head->XCD pinned: (h+16k)&7 = h&7)
  const int ss = 127 - (bid >> 4);        // q-subtile, heavy first
  const int qs = ss * 32;                 // first q row
  const int ntt = ss + 1;                 // causal 32-key tiles
  const int ks0 = w ? (ntt >> 1) : 0;     // this wave's tile range
  const int ks1 = w ? ntt : (ntt >> 1);

  const u16* Qp = Qg + (size_t)(qs + l31) * 1024 + h * 64 + hi * 8;
  const u16* Kp = Kg + (size_t)l31 * 1024 + h * 64 + hi * 8;
  const u16* Vp = Vtg + (size_t)(h * 64 + l31) * 4096 + hi * 8;

  short8 qf[4];
#pragma unroll
  for (int kc = 0; kc < 4; ++kc) qf[kc] = *(const short8*)(Qp + kc * 16);

  short8 kf[4], vf[2][2];
  {
    const u16* K0 = Kp + (size_t)ks0 * 32 * 1024;
    const u16* V0 = Vp + ks0 * 32;
#pragma unroll
    for (int kc = 0; kc < 4; ++kc)
      kf[kc] = *(const short8*)(K0 + kc * 16);
#pragma unroll
    for (int dt = 0; dt < 2; ++dt)
#pragma unroll
      for (int ks = 0; ks < 2; ++ks)
        vf[dt][ks] = *(const short8*)(V0 + (size_t)dt * 131072 + ks * 16);
  }

  f32x16 ot[2] = {};
  float m = NEGINF, lsum = 0.f;

  for (int kt = ks0; kt < ks1; ++kt) {
    const int kbase = kt * 32;

    // S^T = K · Q^T  (4 mfma, 32 keys x 32 queries)
    f32x16 st = {};
#pragma unroll
    for (int kc = 0; kc < 4; ++kc)
      st = __builtin_amdgcn_mfma_f32_32x32x16_bf16(kf[kc], qf[kc], st, 0, 0, 0);

    if (kt + 1 < ks1) {  // prefetch next K tile; overlaps softmax+PV
      const u16* Kn = Kp + (size_t)(kbase + 32) * 1024;
#pragma unroll
      for (int kc = 0; kc < 4; ++kc)
        kf[kc] = *(const short8*)(Kn + kc * 16);
    }

    if (kt == ntt - 1) {  // causal mask, diagonal tile only (wave1)
      const int q = qs + l31;
#pragma unroll
      for (int r = 0; r < 16; ++r) {
        int key = kbase + (r & 3) + 8 * (r >> 2) + 4 * hi;
        if (key > q) st[r] = NEGINF;
      }
    }

    // row max: in-lane tree + one cross-half exchange
    float pm;
    {
      float a0 = fmaxf(st[0], st[1]), a1 = fmaxf(st[2], st[3]);
      float a2 = fmaxf(st[4], st[5]), a3 = fmaxf(st[6], st[7]);
      a0 = fmaxf(a0, fmaxf(st[8], st[9]));
      a1 = fmaxf(a1, fmaxf(st[10], st[11]));
      a2 = fmaxf(a2, fmaxf(st[12], st[13]));
      a3 = fmaxf(a3, fmaxf(st[14], st[15]));
      pm = fmaxf(fmaxf(a0, a1), fmaxf(a2, a3));
      pm = fmaxf(pm, __shfl_xor(pm, 32, 64));
    }

    // defer-max (T13): only rescale when max grew by > 8 (log2 domain)
    if (!__all(pm - m <= 8.f)) {
      float mn = fmaxf(m, pm);
      float al = exp2f(m - mn);
      lsum *= al;
#pragma unroll
      for (int dt = 0; dt < 2; ++dt)
#pragma unroll
        for (int r = 0; r < 16; ++r) ot[dt][r] *= al;
      m = mn;
    }

    float ps = 0.f;
#pragma unroll
    for (int r = 0; r < 16; ++r) {
      float p = exp2f(st[r] - m);
      st[r] = p;
      ps += p;
    }
    ps += __shfl_xor(ps, 32, 64);
    lsum += ps;

    // P -> bf16 B-fragments (v_cvt_pk via __float22bfloat162_rn)
    // pa[ks] elem e holds P^T[key = kbase + 16ks + 8*hi + e][query l31]
    short8 pa[2];
#pragma unroll
    for (int ks = 0; ks < 2; ++ks) {
      const int b = 8 * ks;
      u32 pk0 = pkbf(st[b + 0], st[b + 1]);  // keys 16ks+{0,1}+4hi
      u32 pk1 = pkbf(st[b + 2], st[b + 3]);  // keys 16ks+{2,3}+4hi
      u32 pk2 = pkbf(st[b + 4], st[b + 5]);  // keys 16ks+8+{0,1}+4hi
      u32 pk3 = pkbf(st[b + 6], st[b + 7]);  // keys 16ks+8+{2,3}+4hi
      u32 s0 = (u32)__shfl_xor((int)pk0, 32, 64);
      u32 s1 = (u32)__shfl_xor((int)pk1, 32, 64);
      u32 s2 = (u32)__shfl_xor((int)pk2, 32, 64);
      u32 s3 = (u32)__shfl_xor((int)pk3, 32, 64);
      u32x4 t;
      t.x = hi ? s2 : pk0;
      t.y = hi ? s3 : pk1;
      t.z = hi ? pk2 : s0;
      t.w = hi ? pk3 : s1;
      pa[ks] = __builtin_bit_cast(short8, t);
    }

    // O^T += V^T · P^T  (4 mfma)
#pragma unroll
    for (int dt = 0; dt < 2; ++dt)
#pragma unroll
      for (int ks = 0; ks < 2; ++ks)
        ot[dt] = __builtin_amdgcn_mfma_f32_32x32x16_bf16(vf[dt][ks], pa[ks],
                                                         ot[dt], 0, 0, 0);

    if (kt + 1 < ks1) {  // prefetch next V tile
      const u16* Vn = Vp + kbase + 32;
#pragma unroll
      for (int dt = 0; dt < 2; ++dt)
#pragma unroll
        for (int ks = 0; ks < 2; ++ks)
          vf[dt][ks] = *(const short8*)(Vn + (size_t)dt * 131072 + ks * 16);
    }
  }

  // ---- flash combine of the two KV-halves ------------------------------
  if (w == 0) {
#pragma unroll
    for (int dt = 0; dt < 2; ++dt)
#pragma unroll
      for (int r = 0; r < 16; ++r) {
        int d = dt * 32 + (r & 3) + 8 * (r >> 2) + 4 * hi;
        lOf[d * 32 + l31] = ot[dt][r];
      }
    if (hi == 0) { lm[l31] = m; ll[l31] = lsum; }
  }
  __syncthreads();
  if (w == 1) {
    float mA = lm[l31], lA = ll[l31];
    float mm = fmaxf(mA, m);
    float wA = exp2f(mA - mm), wB = exp2f(m - mm);
    float inv = 1.0f / (lA * wA + lsum * wB);
    char* pw = (char*)lOut;
#pragma unroll
    for (int dt = 0; dt < 2; ++dt)
#pragma unroll
      for (int r = 0; r < 16; ++r) {
        int d = dt * 32 + (r & 3) + 8 * (r >> 2) + 4 * hi;
        float val = (lOf[d * 32 + l31] * wA + ot[dt][r] * wB) * inv;
        *(u16*)(pw + l31 * 128 + ((d * 2) ^ ((l31 & 7) << 4))) = f2b(val);
      }
  }
  __syncthreads();
  if (w == 1) {
    const char* pw = (const char*)lOut;
    const int row = lane >> 1;
#pragma unroll
    for (int ii = 0; ii < 4; ++ii) {
      int c = (lane & 1) * 4 + ii;
      short8 v = *(const short8*)(pw + row * 128 + ((c * 16) ^ ((row & 7) << 4)));
      *(short8*)(Og + (size_t)(qs + row) * 1024 + h * 64 + c * 8) = v;
    }
  }
}

// ---- launcher ----------------------------------------------------------

extern "C" void kernel_launch(void* const* d_in, const int* in_sizes, int n_in,
                              void* d_out, int out_size, void* d_ws, size_t ws_size,
                              hipStream_t stream) {
  const float* x = (const float*)d_in[0];
  const float* Wq = (const float*)d_in[1];
  const float* Wk = (const float*)d_in[2];
  const float* Wv = (const float*)d_in[3];
  const float* Wo = (const float*)d_in[4];
  float* out = (float*)d_out;
  char* ws = (char*)d_ws;
  const size_t MB = 1024 * 1024;

  u16* xb  = (u16*)(ws);
  u16* wqb = (u16*)(ws + 8 * MB);
  u16* wkb = (u16*)(ws + 10 * MB);
  u16* wvb = (u16*)(ws + 12 * MB);
  u16* wob = (u16*)(ws + 14 * MB);
  u16* Qb  = (u16*)(ws + 16 * MB);
  u16* Kb  = (u16*)(ws + 24 * MB);
  u16* Vb  = (u16*)(ws + 32 * MB);
  u16* Vtb = (u16*)(ws + 40 * MB);
  u16* att = xb;

  // 0.125 = 1/sqrt(D); *log2(e) so softmax runs in exp2 domain
  const float qscale = 0.125f * 1.4426950408889634f;

  f2bf_kernel<<<4096, 256, 0, stream>>>(x, xb, 4096 * 1024, 1.f);
  f2bf_kernel<<<1024, 256, 0, stream>>>(Wq, wqb, 1024 * 1024, qscale);
  f2bf_kernel<<<1024, 256, 0, stream>>>(Wk, wkb, 1024 * 1024, 1.f);
  f2bf_kernel<<<1024, 256, 0, stream>>>(Wv, wvb, 1024 * 1024, 1.f);
  f2bf_kernel<<<1024, 256, 0, stream>>>(Wo, wob, 1024 * 1024, 1.f);

  gemm_qkv_kernel<<<dim3(8, 32, 3), 256, 0, stream>>>(xb, wqb, wkb, wvb, Qb, Kb, Vb);
  transpose_kernel<<<dim3(32, 128), 256, 0, stream>>>(Vb, Vtb);
  attn_kernel<<<2048, 128, 0, stream>>>(Qb, Kb, Vtb, att);
  gemm_out_kernel<<<dim3(8, 32), 256, 0, stream>>>(att, wob, out);
}

// Round 7
// 219.104 us; speedup vs baseline: 1.7618x; 1.0072x over previous
//
#include <hip/hip_runtime.h>
#include <hip/hip_bf16.h>

typedef unsigned short u16;
typedef unsigned int u32;
typedef __attribute__((ext_vector_type(8))) short short8;
typedef __attribute__((ext_vector_type(4))) float f32x4;
typedef __attribute__((ext_vector_type(16))) float f32x16;
typedef __attribute__((ext_vector_type(4))) u32 u32x4;
typedef __attribute__((ext_vector_type(2))) u32 u32x2;

// ---- helpers ----------------------------------------------------------

__device__ __forceinline__ u16 f2b(float f) {
  unsigned u = __float_as_uint(f);
  u = (u + 0x7FFFu + ((u >> 16) & 1u)) >> 16;  // RNE
  return (u16)u;
}

__device__ __forceinline__ u32 pkbf(float lo, float hi) {
  __hip_bfloat162 b = __float22bfloat162_rn(make_float2(lo, hi));  // v_cvt_pk_bf16_f32
  u32 r;
  __builtin_memcpy(&r, &b, 4);
  return r;
}

// v_permlane32_swap_b32: r.x = {a.lo_lanes, b.lo_lanes-from-lane-32-view},
// precisely: r.x[l<32]=a[l], r.x[l>=32]=b[l-32]; r.y[l<32]=a[l+32], r.y[l>=32]=b[l].
__device__ __forceinline__ u32x2 plswap(u32 a, u32 b) {
  return __builtin_amdgcn_permlane32_swap(a, b, false, false);
}

__device__ __forceinline__ float xhalf_max(float x) {
  u32x2 r = plswap(__float_as_uint(x), __float_as_uint(x));
  return fmaxf(__uint_as_float(r.x), __uint_as_float(r.y));
}

__device__ __forceinline__ float xhalf_sum(float x) {
  u32x2 r = plswap(__float_as_uint(x), __float_as_uint(x));
  return __uint_as_float(r.x) + __uint_as_float(r.y);
}

__device__ __forceinline__ void gload16(const void* g, void* l) {
  __builtin_amdgcn_global_load_lds(
      (const __attribute__((address_space(1))) void*)g,
      (__attribute__((address_space(3))) void*)l, 16, 0, 0);
}

// ---- fp32 -> bf16 bulk convert (optional scale fold) -------------------

__global__ __launch_bounds__(256) void f2bf_kernel(const float* __restrict__ in,
                                                   u16* __restrict__ out, int n,
                                                   float scale) {
  int i = (blockIdx.x * 256 + threadIdx.x) * 4;
  if (i >= n) return;
  float4 v = *(const float4*)(in + i);
  unsigned p0 = (unsigned)f2b(v.x * scale) | ((unsigned)f2b(v.y * scale) << 16);
  unsigned p1 = (unsigned)f2b(v.z * scale) | ((unsigned)f2b(v.w * scale) << 16);
  *(uint2*)(out + i) = make_uint2(p0, p1);
}

// ---- bf16 transpose: V[4096][1024] -> Vt[1024][4096] -------------------

__global__ __launch_bounds__(256) void transpose_kernel(const u16* __restrict__ V,
                                                        u16* __restrict__ Vt) {
  __shared__ u16 t[32][33];
  int bx = blockIdx.x;
  int by = blockIdx.y;
  int c = threadIdx.x & 31, r4 = threadIdx.x >> 5;
#pragma unroll
  for (int i = 0; i < 4; ++i) {
    int row = r4 * 4 + i;
    t[row][c] = V[(size_t)(by * 32 + row) * 1024 + bx * 32 + c];
  }
  __syncthreads();
#pragma unroll
  for (int i = 0; i < 4; ++i) {
    int row = r4 * 4 + i;
    Vt[(size_t)(bx * 32 + row) * 4096 + by * 32 + c] = t[c][row];
  }
}

// ---- GEMM: C[4096][1024] = A[4096][1024] @ B[1024][1024]^T (bf16) ------

__device__ __forceinline__ void storeC(u16* C, size_t idx, float v) { C[idx] = f2b(v); }
__device__ __forceinline__ void storeC(float* C, size_t idx, float v) { C[idx] = v; }

template <typename OutT>
__device__ __forceinline__ void gemm_body(const u16* __restrict__ A,
                                          const u16* __restrict__ B,
                                          OutT* __restrict__ C) {
  __shared__ __align__(16) u16 lA[128 * 32];
  __shared__ __align__(16) u16 lB[128 * 32];
  const int tid = threadIdx.x;
  const int w = tid >> 6, lane = tid & 63, g = lane >> 4, lr = lane & 15;
  const int wr = w >> 1, wc = w & 1;
  const int m0 = blockIdx.y * 128, n0 = blockIdx.x * 128;

  f32x4 acc[4][4] = {};

  for (int k0 = 0; k0 < 1024; k0 += 32) {
#pragma unroll
    for (int j = 0; j < 2; ++j) {
      int c = tid + j * 256;
      gload16(A + (size_t)(m0 + (c >> 2)) * 1024 + k0 + (c & 3) * 8,
              &lA[(j * 256 + w * 64) * 8]);
      gload16(B + (size_t)(n0 + (c >> 2)) * 1024 + k0 + (c & 3) * 8,
              &lB[(j * 256 + w * 64) * 8]);
    }
    __syncthreads();

    short8 af[4], bf[4];
#pragma unroll
    for (int i = 0; i < 4; ++i) {
      af[i] = *(const short8*)&lA[(wr * 64 + i * 16 + lr) * 32 + g * 8];
      bf[i] = *(const short8*)&lB[(wc * 64 + i * 16 + lr) * 32 + g * 8];
    }
#pragma unroll
    for (int mi = 0; mi < 4; ++mi)
#pragma unroll
      for (int ni = 0; ni < 4; ++ni)
        acc[mi][ni] =
            __builtin_amdgcn_mfma_f32_16x16x32_bf16(af[mi], bf[ni], acc[mi][ni], 0, 0, 0);
    __syncthreads();
  }

#pragma unroll
  for (int mi = 0; mi < 4; ++mi)
#pragma unroll
    for (int ni = 0; ni < 4; ++ni)
#pragma unroll
      for (int r = 0; r < 4; ++r) {
        size_t row = (size_t)(m0 + wr * 64 + mi * 16 + g * 4 + r);
        size_t col = (size_t)(n0 + wc * 64 + ni * 16 + lr);
        storeC(C, row * 1024 + col, acc[mi][ni][r]);
      }
}

__global__ __launch_bounds__(256) void gemm_qkv_kernel(
    const u16* __restrict__ A, const u16* __restrict__ W0, const u16* __restrict__ W1,
    const u16* __restrict__ W2, u16* __restrict__ C0, u16* __restrict__ C1,
    u16* __restrict__ C2) {
  int z = blockIdx.z;
  const u16* B = (z == 0) ? W0 : (z == 1) ? W1 : W2;
  u16* C = (z == 0) ? C0 : (z == 1) ? C1 : C2;
  gemm_body<u16>(A, B, C);
}

__global__ __launch_bounds__(256) void gemm_out_kernel(const u16* __restrict__ A,
                                                       const u16* __restrict__ B,
                                                       float* __restrict__ C) {
  gemm_body<float>(A, B, C);
}

// ---- flash attention, swapped-operand 32x32, KV-split x2 ---------------
// block = 128 thr = 2 waves sharing ONE 32-row q-subtile of one head.
// 32-key tiles; (128,4): 4 waves/SIMD (spill tripwire = WRITE_SIZE).
// Main loop has ZERO LDS ops: reductions & P-fragment routing use
// v_permlane32_swap_b32 (T12 primitive), pack via v_cvt_pk_bf16_f32.
// S^T = mfma(K, Q): col=query=lane&31, row=key=(r&3)+8*(r>>2)+4*hi.
// O^T = mfma(V^T, P^T): col=query (lane-local), row=d.
// Q pre-scaled by 0.125*log2e -> softmax in exp2 domain. Mask = -30000.

#define NEGINF (-30000.0f)

__global__ __launch_bounds__(128, 4) void attn_kernel(const u16* __restrict__ Qg,
                                                      const u16* __restrict__ Kg,
                                                      const u16* __restrict__ Vtg,
                                                      u16* __restrict__ Og) {
  __shared__ __align__(16) float lOf[64 * 32];  // 8KB: wave0's O^T (f32)
  __shared__ float lm[32], ll[32];
  __shared__ __align__(16) u16 lOut[32 * 64];   // 4KB: bf16 out transpose
  const int tid = threadIdx.x, w = tid >> 6, lane = tid & 63;
  const int l31 = lane & 31, hi = lane >> 5;
  const int bid = blockIdx.x;
  const int h = bid & 15;                 // head (head->XCD pinned)
  const int ss = 127 - (bid >> 4);        // q-subtile, heavy first
  const int qs = ss * 32;                 // first q row
  const int ntt = ss + 1;                 // causal 32-key tiles
  const int ks0 = w ? (ntt >> 1) : 0;     // this wave's tile range
  const int ks1 = w ? ntt : (ntt >> 1);

  const u16* Qp = Qg + (size_t)(qs + l31) * 1024 + h * 64 + hi * 8;
  const u16* Kp = Kg + (size_t)l31 * 1024 + h * 64 + hi * 8;
  const u16* Vp = Vtg + (size_t)(h * 64 + l31) * 4096 + hi * 8;

  short8 qf[4];
#pragma unroll
  for (int kc = 0; kc < 4; ++kc) qf[kc] = *(const short8*)(Qp + kc * 16);

  short8 kf[4], vf[2][2];
  {
    const u16* K0 = Kp + (size_t)ks0 * 32 * 1024;
    const u16* V0 = Vp + ks0 * 32;
#pragma unroll
    for (int kc = 0; kc < 4; ++kc)
      kf[kc] = *(const short8*)(K0 + kc * 16);
#pragma unroll
    for (int dt = 0; dt < 2; ++dt)
#pragma unroll
      for (int ks = 0; ks < 2; ++ks)
        vf[dt][ks] = *(const short8*)(V0 + (size_t)dt * 131072 + ks * 16);
  }

  f32x16 ot[2] = {};
  float m = NEGINF, lsum = 0.f;

  for (int kt = ks0; kt < ks1; ++kt) {
    const int kbase = kt * 32;

    // S^T = K · Q^T  (4 mfma, 32 keys x 32 queries)
    f32x16 st = {};
#pragma unroll
    for (int kc = 0; kc < 4; ++kc)
      st = __builtin_amdgcn_mfma_f32_32x32x16_bf16(kf[kc], qf[kc], st, 0, 0, 0);

    if (kt + 1 < ks1) {  // prefetch next K tile; overlaps softmax+PV
      const u16* Kn = Kp + (size_t)(kbase + 32) * 1024;
#pragma unroll
      for (int kc = 0; kc < 4; ++kc)
        kf[kc] = *(const short8*)(Kn + kc * 16);
    }

    if (kt == ntt - 1) {  // causal mask, diagonal tile only (wave1)
      const int q = qs + l31;
#pragma unroll
      for (int r = 0; r < 16; ++r) {
        int key = kbase + (r & 3) + 8 * (r >> 2) + 4 * hi;
        if (key > q) st[r] = NEGINF;
      }
    }

    // row max: v_max3-shaped in-lane tree + one permlane cross-half
    float pm;
    {
      float a0 = fmaxf(fmaxf(st[0], st[1]), st[2]);
      float a1 = fmaxf(fmaxf(st[3], st[4]), st[5]);
      float a2 = fmaxf(fmaxf(st[6], st[7]), st[8]);
      float a3 = fmaxf(fmaxf(st[9], st[10]), st[11]);
      float a4 = fmaxf(fmaxf(st[12], st[13]), st[14]);
      float b0 = fmaxf(fmaxf(a0, a1), a2);
      float b1 = fmaxf(fmaxf(a3, a4), st[15]);
      pm = xhalf_max(fmaxf(b0, b1));
    }

    // defer-max (T13): only rescale when max grew by > 8 (log2 domain)
    if (!__all(pm - m <= 8.f)) {
      float mn = fmaxf(m, pm);
      float al = exp2f(m - mn);
      lsum *= al;
#pragma unroll
      for (int dt = 0; dt < 2; ++dt)
#pragma unroll
        for (int r = 0; r < 16; ++r) ot[dt][r] *= al;
      m = mn;
    }

    float ps = 0.f;
#pragma unroll
    for (int r = 0; r < 16; ++r) {
      float p = exp2f(st[r] - m);
      st[r] = p;
      ps += p;
    }
    lsum += xhalf_sum(ps);

    // P -> bf16 B-fragments: cvt_pk + permlane32_swap (no bpermute/select)
    // pa[ks] elem e holds P^T[key = kbase + 16ks + 8*hi + e][query l31]
    short8 pa[2];
#pragma unroll
    for (int ks = 0; ks < 2; ++ks) {
      const int b = 8 * ks;
      u32 pk0 = pkbf(st[b + 0], st[b + 1]);  // keys {0,1}+4hi
      u32 pk1 = pkbf(st[b + 2], st[b + 3]);  // keys {2,3}+4hi
      u32 pk2 = pkbf(st[b + 4], st[b + 5]);  // keys 8+{0,1}+4hi
      u32 pk3 = pkbf(st[b + 6], st[b + 7]);  // keys 8+{2,3}+4hi
      u32x2 r02 = plswap(pk0, pk2);  // r02.x = frag word0, r02.y = word2
      u32x2 r13 = plswap(pk1, pk3);  // r13.x = word1, r13.y = word3
      u32x4 t;
      t.x = r02.x;
      t.y = r13.x;
      t.z = r02.y;
      t.w = r13.y;
      pa[ks] = __builtin_bit_cast(short8, t);
    }

    // O^T += V^T · P^T  (4 mfma)
#pragma unroll
    for (int dt = 0; dt < 2; ++dt)
#pragma unroll
      for (int ks = 0; ks < 2; ++ks)
        ot[dt] = __builtin_amdgcn_mfma_f32_32x32x16_bf16(vf[dt][ks], pa[ks],
                                                         ot[dt], 0, 0, 0);

    if (kt + 1 < ks1) {  // prefetch next V tile
      const u16* Vn = Vp + kbase + 32;
#pragma unroll
      for (int dt = 0; dt < 2; ++dt)
#pragma unroll
        for (int ks = 0; ks < 2; ++ks)
          vf[dt][ks] = *(const short8*)(Vn + (size_t)dt * 131072 + ks * 16);
    }
  }

  // ---- flash combine of the two KV-halves ------------------------------
  if (w == 0) {
#pragma unroll
    for (int dt = 0; dt < 2; ++dt)
#pragma unroll
      for (int r = 0; r < 16; ++r) {
        int d = dt * 32 + (r & 3) + 8 * (r >> 2) + 4 * hi;
        lOf[d * 32 + l31] = ot[dt][r];
      }
    if (hi == 0) { lm[l31] = m; ll[l31] = lsum; }
  }
  __syncthreads();
  if (w == 1) {
    float mA = lm[l31], lA = ll[l31];
    float mm = fmaxf(mA, m);
    float wA = exp2f(mA - mm), wB = exp2f(m - mm);
    float inv = 1.0f / (lA * wA + lsum * wB);
    char* pw = (char*)lOut;
#pragma unroll
    for (int dt = 0; dt < 2; ++dt)
#pragma unroll
      for (int r = 0; r < 16; ++r) {
        int d = dt * 32 + (r & 3) + 8 * (r >> 2) + 4 * hi;
        float val = (lOf[d * 32 + l31] * wA + ot[dt][r] * wB) * inv;
        *(u16*)(pw + l31 * 128 + ((d * 2) ^ ((l31 & 7) << 4))) = f2b(val);
      }
  }
  __syncthreads();
  if (w == 1) {
    const char* pw = (const char*)lOut;
    const int row = lane >> 1;
#pragma unroll
    for (int ii = 0; ii < 4; ++ii) {
      int c = (lane & 1) * 4 + ii;
      short8 v = *(const short8*)(pw + row * 128 + ((c * 16) ^ ((row & 7) << 4)));
      *(short8*)(Og + (size_t)(qs + row) * 1024 + h * 64 + c * 8) = v;
    }
  }
}

// ---- launcher ----------------------------------------------------------

extern "C" void kernel_launch(void* const* d_in, const int* in_sizes, int n_in,
                              void* d_out, int out_size, void* d_ws, size_t ws_size,
                              hipStream_t stream) {
  const float* x = (const float*)d_in[0];
  const float* Wq = (const float*)d_in[1];
  const float* Wk = (const float*)d_in[2];
  const float* Wv = (const float*)d_in[3];
  const float* Wo = (const float*)d_in[4];
  float* out = (float*)d_out;
  char* ws = (char*)d_ws;
  const size_t MB = 1024 * 1024;

  u16* xb  = (u16*)(ws);
  u16* wqb = (u16*)(ws + 8 * MB);
  u16* wkb = (u16*)(ws + 10 * MB);
  u16* wvb = (u16*)(ws + 12 * MB);
  u16* wob = (u16*)(ws + 14 * MB);
  u16* Qb  = (u16*)(ws + 16 * MB);
  u16* Kb  = (u16*)(ws + 24 * MB);
  u16* Vb  = (u16*)(ws + 32 * MB);
  u16* Vtb = (u16*)(ws + 40 * MB);
  u16* att = xb;

  // 0.125 = 1/sqrt(D); *log2(e) so softmax runs in exp2 domain
  const float qscale = 0.125f * 1.4426950408889634f;

  f2bf_kernel<<<4096, 256, 0, stream>>>(x, xb, 4096 * 1024, 1.f);
  f2bf_kernel<<<1024, 256, 0, stream>>>(Wq, wqb, 1024 * 1024, qscale);
  f2bf_kernel<<<1024, 256, 0, stream>>>(Wk, wkb, 1024 * 1024, 1.f);
  f2bf_kernel<<<1024, 256, 0, stream>>>(Wv, wvb, 1024 * 1024, 1.f);
  f2bf_kernel<<<1024, 256, 0, stream>>>(Wo, wob, 1024 * 1024, 1.f);

  gemm_qkv_kernel<<<dim3(8, 32, 3), 256, 0, stream>>>(xb, wqb, wkb, wvb, Qb, Kb, Vb);
  transpose_kernel<<<dim3(32, 128), 256, 0, stream>>>(Vb, Vtb);
  attn_kernel<<<2048, 128, 0, stream>>>(Qb, Kb, Vtb, att);
  gemm_out_kernel<<<dim3(8, 32), 256, 0, stream>>>(att, wob, out);
}

// Round 9
// 163.417 us; speedup vs baseline: 2.3622x; 1.3408x over previous
//
#include <hip/hip_runtime.h>
#include <hip/hip_bf16.h>

typedef unsigned short u16;
typedef unsigned int u32;
typedef __attribute__((ext_vector_type(8))) short short8;
typedef __attribute__((ext_vector_type(4))) float f32x4;
typedef __attribute__((ext_vector_type(16))) float f32x16;
typedef __attribute__((ext_vector_type(4))) u32 u32x4;
typedef __attribute__((ext_vector_type(2))) u32 u32x2;

// ---- helpers ----------------------------------------------------------

__device__ __forceinline__ u16 f2b(float f) {
  unsigned u = __float_as_uint(f);
  u = (u + 0x7FFFu + ((u >> 16) & 1u)) >> 16;  // RNE
  return (u16)u;
}

__device__ __forceinline__ u32 pkbf(float lo, float hi) {
  __hip_bfloat162 b = __float22bfloat162_rn(make_float2(lo, hi));  // v_cvt_pk_bf16_f32
  u32 r;
  __builtin_memcpy(&r, &b, 4);
  return r;
}

__device__ __forceinline__ u32x2 plswap(u32 a, u32 b) {
  return __builtin_amdgcn_permlane32_swap(a, b, false, false);
}

__device__ __forceinline__ float xhalf_max(float x) {
  u32x2 r = plswap(__float_as_uint(x), __float_as_uint(x));
  return fmaxf(__uint_as_float(r.x), __uint_as_float(r.y));
}

__device__ __forceinline__ float xhalf_sum(float x) {
  u32x2 r = plswap(__float_as_uint(x), __float_as_uint(x));
  return __uint_as_float(r.x) + __uint_as_float(r.y);
}

__device__ __forceinline__ void gload16(const void* g, void* l) {
  __builtin_amdgcn_global_load_lds(
      (const __attribute__((address_space(1))) void*)g,
      (__attribute__((address_space(3))) void*)l, 16, 0, 0);
}

// ---- fp32 -> bf16 bulk convert (optional scale fold) -------------------

__global__ __launch_bounds__(256) void f2bf_kernel(const float* __restrict__ in,
                                                   u16* __restrict__ out, int n,
                                                   float scale) {
  int i = (blockIdx.x * 256 + threadIdx.x) * 4;
  if (i >= n) return;
  float4 v = *(const float4*)(in + i);
  unsigned p0 = (unsigned)f2b(v.x * scale) | ((unsigned)f2b(v.y * scale) << 16);
  unsigned p1 = (unsigned)f2b(v.z * scale) | ((unsigned)f2b(v.w * scale) << 16);
  *(uint2*)(out + i) = make_uint2(p0, p1);
}

// ---- bf16 transpose: V[4096][1024] -> Vt[1024][4096] -------------------

__global__ __launch_bounds__(256) void transpose_kernel(const u16* __restrict__ V,
                                                        u16* __restrict__ Vt) {
  __shared__ u16 t[32][33];
  int bx = blockIdx.x;
  int by = blockIdx.y;
  int c = threadIdx.x & 31, r4 = threadIdx.x >> 5;
#pragma unroll
  for (int i = 0; i < 4; ++i) {
    int row = r4 * 4 + i;
    t[row][c] = V[(size_t)(by * 32 + row) * 1024 + bx * 32 + c];
  }
  __syncthreads();
#pragma unroll
  for (int i = 0; i < 4; ++i) {
    int row = r4 * 4 + i;
    Vt[(size_t)(bx * 32 + row) * 4096 + by * 32 + c] = t[c][row];
  }
}

// ---- GEMM: C[4096][1024] = A[4096][1024] @ B[1024][1024]^T (bf16) ------

__device__ __forceinline__ void storeC(u16* C, size_t idx, float v) { C[idx] = f2b(v); }
__device__ __forceinline__ void storeC(float* C, size_t idx, float v) { C[idx] = v; }

template <typename OutT>
__device__ __forceinline__ void gemm_body(const u16* __restrict__ A,
                                          const u16* __restrict__ B,
                                          OutT* __restrict__ C) {
  __shared__ __align__(16) u16 lA[128 * 32];
  __shared__ __align__(16) u16 lB[128 * 32];
  const int tid = threadIdx.x;
  const int w = tid >> 6, lane = tid & 63, g = lane >> 4, lr = lane & 15;
  const int wr = w >> 1, wc = w & 1;
  const int m0 = blockIdx.y * 128, n0 = blockIdx.x * 128;

  f32x4 acc[4][4] = {};

  for (int k0 = 0; k0 < 1024; k0 += 32) {
#pragma unroll
    for (int j = 0; j < 2; ++j) {
      int c = tid + j * 256;
      gload16(A + (size_t)(m0 + (c >> 2)) * 1024 + k0 + (c & 3) * 8,
              &lA[(j * 256 + w * 64) * 8]);
      gload16(B + (size_t)(n0 + (c >> 2)) * 1024 + k0 + (c & 3) * 8,
              &lB[(j * 256 + w * 64) * 8]);
    }
    __syncthreads();

    short8 af[4], bf[4];
#pragma unroll
    for (int i = 0; i < 4; ++i) {
      af[i] = *(const short8*)&lA[(wr * 64 + i * 16 + lr) * 32 + g * 8];
      bf[i] = *(const short8*)&lB[(wc * 64 + i * 16 + lr) * 32 + g * 8];
    }
#pragma unroll
    for (int mi = 0; mi < 4; ++mi)
#pragma unroll
      for (int ni = 0; ni < 4; ++ni)
        acc[mi][ni] =
            __builtin_amdgcn_mfma_f32_16x16x32_bf16(af[mi], bf[ni], acc[mi][ni], 0, 0, 0);
    __syncthreads();
  }

#pragma unroll
  for (int mi = 0; mi < 4; ++mi)
#pragma unroll
    for (int ni = 0; ni < 4; ++ni)
#pragma unroll
      for (int r = 0; r < 4; ++r) {
        size_t row = (size_t)(m0 + wr * 64 + mi * 16 + g * 4 + r);
        size_t col = (size_t)(n0 + wc * 64 + ni * 16 + lr);
        storeC(C, row * 1024 + col, acc[mi][ni][r]);
      }
}

__global__ __launch_bounds__(256) void gemm_qkv_kernel(
    const u16* __restrict__ A, const u16* __restrict__ W0, const u16* __restrict__ W1,
    const u16* __restrict__ W2, u16* __restrict__ C0, u16* __restrict__ C1,
    u16* __restrict__ C2) {
  int z = blockIdx.z;
  const u16* B = (z == 0) ? W0 : (z == 1) ? W1 : W2;
  u16* C = (z == 0) ? C0 : (z == 1) ? C1 : C2;
  gemm_body<u16>(A, B, C);
}

__global__ __launch_bounds__(256) void gemm_out_kernel(const u16* __restrict__ A,
                                                       const u16* __restrict__ B,
                                                       float* __restrict__ C) {
  gemm_body<float>(A, B, C);
}

// ---- flash attention: LDS-staged KV, q-share x4, KV-split x2 -----------
// block = 512 thr = 8 waves = 2 pairs x 4 q-subtiles; 128 q rows, 1 head.
// Pair p streams 64-key K/V tiles, staged to LDS via global_load_lds
// (128B-contiguous rows) with XOR-swizzled source + swizzled ds_read.
// Double-buffered, 1 barrier/tile. 4 q-waves share the staged stream.
// Swapped-operand MFMAs: S^T = mfma(K,Q), O^T = mfma(V^T,P^T); pack via
// cvt_pk + permlane32_swap. Flash combine per q-subtile.
// Causal mask applies whenever kt == dtw, in EITHER pair (r8 bug: at qb=0
// the diagonal tile of qw 0/1 lies in pair 0's range). Mask = -30000.

#define NEGINF (-30000.0f)

__global__ __launch_bounds__(512, 4) void attn_kernel(const u16* __restrict__ Qg,
                                                      const u16* __restrict__ Kg,
                                                      const u16* __restrict__ Vtg,
                                                      u16* __restrict__ Og) {
  // [pair][buf][K/V][8KB] = 64KB; reused by the epilogue as lOf (32KB) + lOut (16KB)
  __shared__ __align__(16) char smem[65536];
  __shared__ float lmm[4][32], lll[4][32];

  const int tid = threadIdx.x, lane = tid & 63;
  const int w8 = tid >> 6, p = w8 >> 2, qw = w8 & 3;
  const int l31 = lane & 31, hi = lane >> 5;
  const int bid = blockIdx.x;
  const int h = bid & 15;                    // head (head->XCD pinned)
  const int i32 = bid >> 4;                  // 0..31
  const int qb = (i32 < 16) ? (31 - i32) : (i32 - 16);  // heavy/light pairing
  const int qs = qb * 128;                   // block's first q row
  const int qsw = qs + qw * 32;              // wave's first q row
  const int iters = qb + 1;                  // tiles per pair (64-key tiles)
  const int kstart = p ? iters : 0;
  const int dtw = qsw >> 6;                  // wave's diagonal 64-key tile
  const int swz = (l31 & 7) << 4;

  // Q fragment (A-operand rows = queries)
  short8 qf[4];
  {
    const u16* Qp = Qg + (size_t)(qsw + l31) * 1024 + h * 64 + hi * 8;
#pragma unroll
    for (int kc = 0; kc < 4; ++kc) qf[kc] = *(const short8*)(Qp + kc * 16);
  }

  // stage one 64-key tile (K: [64 keys][128B], Vt: [64 d][128B]) for pair p.
  const int j0 = qw * 2;
  auto stage = [&](int b, int kt) {
    char* Kb = smem + (((p << 1) | b) << 14);
    char* Vb = Kb + 8192;
#pragma unroll
    for (int jj = 0; jj < 2; ++jj) {
      const int j = j0 + jj;
      const int row = (j << 3) + (lane >> 3);
      const int c = (lane & 7) ^ (row & 7);  // inverse-swizzled source chunk
      gload16(Kg + (size_t)(kt * 64 + row) * 1024 + h * 64 + c * 8,
              Kb + (j << 10));
      gload16(Vtg + (size_t)(h * 64 + row) * 4096 + kt * 64 + c * 8,
              Vb + (j << 10));
    }
  };

  f32x16 ot[2] = {};
  float m = NEGINF, lsum = 0.f;

  int cur = 0;
  stage(0, kstart);
  __syncthreads();

  for (int it = 0; it < iters; ++it) {
    const int kt = kstart + it;
    if (it + 1 < iters) stage(cur ^ 1, kt + 1);

    const bool doCompute = (p == 0) || (kt <= dtw);
    if (doCompute) {
      const char* Kb = smem + (((p << 1) | cur) << 14);
      const char* Vb = Kb + 8192;

      // S^T = K . Q^T for two 32-key subtiles
      f32x16 st0 = {}, st1 = {};
#pragma unroll
      for (int kc = 0; kc < 4; ++kc) {
        short8 k0 = *(const short8*)(Kb + l31 * 128 + ((((kc << 1) | hi) << 4) ^ swz));
        st0 = __builtin_amdgcn_mfma_f32_32x32x16_bf16(k0, qf[kc], st0, 0, 0, 0);
      }
#pragma unroll
      for (int kc = 0; kc < 4; ++kc) {
        short8 k1 =
            *(const short8*)(Kb + 4096 + l31 * 128 + ((((kc << 1) | hi) << 4) ^ swz));
        st1 = __builtin_amdgcn_mfma_f32_32x32x16_bf16(k1, qf[kc], st1, 0, 0, 0);
      }

      if (kt == dtw) {  // causal mask on the diagonal tile (either pair)
        const int q = qsw + l31;
#pragma unroll
        for (int r = 0; r < 16; ++r) {
          int key = kt * 64 + (r & 3) + 8 * (r >> 2) + 4 * hi;
          if (key > q) st0[r] = NEGINF;
          if (key + 32 > q) st1[r] = NEGINF;
        }
      }

      // row max (64 keys): in-lane tree + one permlane cross-half
      float pm;
      {
        float a0 = NEGINF, a1 = NEGINF, a2 = NEGINF, a3 = NEGINF;
#pragma unroll
        for (int r = 0; r < 4; ++r) {
          a0 = fmaxf(a0, fmaxf(st0[r], st1[r]));
          a1 = fmaxf(a1, fmaxf(st0[r + 4], st1[r + 4]));
          a2 = fmaxf(a2, fmaxf(st0[r + 8], st1[r + 8]));
          a3 = fmaxf(a3, fmaxf(st0[r + 12], st1[r + 12]));
        }
        pm = xhalf_max(fmaxf(fmaxf(a0, a1), fmaxf(a2, a3)));
      }

      // defer-max (T13)
      if (!__all(pm - m <= 8.f)) {
        float mn = fmaxf(m, pm);
        float al = exp2f(m - mn);
        lsum *= al;
#pragma unroll
        for (int dt = 0; dt < 2; ++dt)
#pragma unroll
          for (int r = 0; r < 16; ++r) ot[dt][r] *= al;
        m = mn;
      }

      float ps = 0.f;
#pragma unroll
      for (int r = 0; r < 16; ++r) {
        float p0 = exp2f(st0[r] - m);
        float p1 = exp2f(st1[r] - m);
        st0[r] = p0;
        st1[r] = p1;
        ps += p0 + p1;
      }
      lsum += xhalf_sum(ps);

      // per-subtile: pack P -> bf16 B-frags, then PV MFMAs
#pragma unroll
      for (int kt2 = 0; kt2 < 2; ++kt2) {
        const f32x16& st = kt2 ? st1 : st0;
        short8 pa[2];
#pragma unroll
        for (int ks = 0; ks < 2; ++ks) {
          const int b = 8 * ks;
          u32 pk0 = pkbf(st[b + 0], st[b + 1]);
          u32 pk1 = pkbf(st[b + 2], st[b + 3]);
          u32 pk2 = pkbf(st[b + 4], st[b + 5]);
          u32 pk3 = pkbf(st[b + 6], st[b + 7]);
          u32x2 r02 = plswap(pk0, pk2);
          u32x2 r13 = plswap(pk1, pk3);
          u32x4 t;
          t.x = r02.x;
          t.y = r13.x;
          t.z = r02.y;
          t.w = r13.y;
          pa[ks] = __builtin_bit_cast(short8, t);
        }
#pragma unroll
        for (int dt = 0; dt < 2; ++dt)
#pragma unroll
          for (int ks = 0; ks < 2; ++ks) {
            short8 vfv = *(const short8*)(Vb + dt * 4096 + l31 * 128 +
                                          (((kt2 * 4 + ks * 2 + hi) << 4) ^ swz));
            ot[dt] =
                __builtin_amdgcn_mfma_f32_32x32x16_bf16(vfv, pa[ks], ot[dt], 0, 0, 0);
          }
      }
    }
    __syncthreads();
    cur ^= 1;
  }

  // ---- flash combine of the two KV-halves, per q-subtile ----------------
  __syncthreads();  // done with staging buffers; repurpose smem
  float* lOfw = (float*)smem + (qw << 11);              // 8KB per subtile
  char* pw = smem + 32768 + (qw << 12);                 // 4KB per subtile
  if (p == 0) {
#pragma unroll
    for (int dt = 0; dt < 2; ++dt)
#pragma unroll
      for (int r = 0; r < 16; ++r) {
        int d = dt * 32 + (r & 3) + 8 * (r >> 2) + 4 * hi;
        lOfw[d * 32 + l31] = ot[dt][r];
      }
    if (hi == 0) { lmm[qw][l31] = m; lll[qw][l31] = lsum; }
  }
  __syncthreads();
  if (p == 1) {
    float mA = lmm[qw][l31], lA = lll[qw][l31];
    float mm = fmaxf(mA, m);
    float wA = exp2f(mA - mm), wB = exp2f(m - mm);
    float inv = 1.0f / (lA * wA + lsum * wB);
#pragma unroll
    for (int dt = 0; dt < 2; ++dt)
#pragma unroll
      for (int r = 0; r < 16; ++r) {
        int d = dt * 32 + (r & 3) + 8 * (r >> 2) + 4 * hi;
        float val = (lOfw[d * 32 + l31] * wA + ot[dt][r] * wB) * inv;
        *(u16*)(pw + l31 * 128 + ((d * 2) ^ ((l31 & 7) << 4))) = f2b(val);
      }
  }
  __syncthreads();
  if (p == 1) {
    const int row = lane >> 1;
#pragma unroll
    for (int ii = 0; ii < 4; ++ii) {
      int c = (lane & 1) * 4 + ii;
      short8 v = *(const short8*)(pw + row * 128 + ((c * 16) ^ ((row & 7) << 4)));
      *(short8*)(Og + (size_t)(qsw + row) * 1024 + h * 64 + c * 8) = v;
    }
  }
}

// ---- launcher ----------------------------------------------------------

extern "C" void kernel_launch(void* const* d_in, const int* in_sizes, int n_in,
                              void* d_out, int out_size, void* d_ws, size_t ws_size,
                              hipStream_t stream) {
  const float* x = (const float*)d_in[0];
  const float* Wq = (const float*)d_in[1];
  const float* Wk = (const float*)d_in[2];
  const float* Wv = (const float*)d_in[3];
  const float* Wo = (const float*)d_in[4];
  float* out = (float*)d_out;
  char* ws = (char*)d_ws;
  const size_t MB = 1024 * 1024;

  u16* xb  = (u16*)(ws);
  u16* wqb = (u16*)(ws + 8 * MB);
  u16* wkb = (u16*)(ws + 10 * MB);
  u16* wvb = (u16*)(ws + 12 * MB);
  u16* wob = (u16*)(ws + 14 * MB);
  u16* Qb  = (u16*)(ws + 16 * MB);
  u16* Kb  = (u16*)(ws + 24 * MB);
  u16* Vb  = (u16*)(ws + 32 * MB);
  u16* Vtb = (u16*)(ws + 40 * MB);
  u16* att = xb;

  // 0.125 = 1/sqrt(D); *log2(e) so softmax runs in exp2 domain
  const float qscale = 0.125f * 1.4426950408889634f;

  f2bf_kernel<<<4096, 256, 0, stream>>>(x, xb, 4096 * 1024, 1.f);
  f2bf_kernel<<<1024, 256, 0, stream>>>(Wq, wqb, 1024 * 1024, qscale);
  f2bf_kernel<<<1024, 256, 0, stream>>>(Wk, wkb, 1024 * 1024, 1.f);
  f2bf_kernel<<<1024, 256, 0, stream>>>(Wv, wvb, 1024 * 1024, 1.f);
  f2bf_kernel<<<1024, 256, 0, stream>>>(Wo, wob, 1024 * 1024, 1.f);

  gemm_qkv_kernel<<<dim3(8, 32, 3), 256, 0, stream>>>(xb, wqb, wkb, wvb, Qb, Kb, Vb);
  transpose_kernel<<<dim3(32, 128), 256, 0, stream>>>(Vb, Vtb);
  attn_kernel<<<512, 512, 0, stream>>>(Qb, Kb, Vtb, att);
  gemm_out_kernel<<<dim3(8, 32), 256, 0, stream>>>(att, wob, out);
}